// Round 2
// baseline (81.806 us; speedup 1.0000x reference)
//
#include <hip/hip_runtime.h>

// CapsuleConv2d: x (4,32,56,56) f32, weight (P_out=4,P_in=4,K=9,L_in=8,L_out=16) f32
// out (4,64,56,56) f32. 3x3 conv s1 p1, 3 routing iterations.
//
// Lane = dq(bits 0-1: d-quarter) x wl(bits 2-3: 4 w-sites) x p(bits 4-5: plane).
// dq in the QUAD bits so the d-reduction (squash norm, logit updates) is two DPP
// quad_perm adds (pure VALU, no DS pipe).
//
// R8: x halo staged in LDS (conflict-free ch-fastest layout) -- NEUTRAL. Priors'
// global loads were already latency-hidden; kernel (~38 us behind the ~40 us
// harness ws-fill) is STALL-bound: routing's serialized DPP/trans chains at only
// 4 waves/SIMD (live set ~120 VGPR), 6.125 waves/SIMD of work -> batch 2 runs
// nearly bare. Issue floor is ~10 us; we're at ~38.
//
// R9 (this round): T=2 -> T=1. Each wave owns ONE site-row of 4 sites:
// M[9][4] = 36 VGPRs (was 72), live set ~85-95 -> target 5-6 waves/SIMD resident,
// grid doubles to 12544 waves (12.25/SIMD of work) for real latency hiding of the
// routing chains. Block = 2 rows x 8 cols (4 waves), grid y = 28x7 = 196.
// Cost: weight ds_read_b128 feeds 4 sites instead of 8 (+~10% LDS issue) --
// cheap at 25% issue efficiency.
//
// REGISTER LESSONS (R3-R6): any occupancy attribute caused forced spills
// (84/64/128-cap -> up to 887 MB scratch). NO attributes + unroll(disable) on the
// l-loop keeps the live set down and scratch at zero.

#define HW 56
#define HW2 3136
#define WSTRIDE 1168
#define XSTR 33            // (r*10+c) stride in floats, +1 pad for bank spread
#define XN (40 * XSTR)     // 1320 floats = 5280 B

// sum over the 4 lanes of a quad: x + quad_perm[1,0,3,2] then + quad_perm[2,3,0,1]
__device__ __forceinline__ float quad_add1(float x) {
    int y = __builtin_amdgcn_update_dpp(0, __float_as_int(x), 0xB1, 0xF, 0xF, true);
    return x + __int_as_float(y);
}
__device__ __forceinline__ float quad_add2(float x) {
    int y = __builtin_amdgcn_update_dpp(0, __float_as_int(x), 0x4E, 0xF, 0xF, true);
    return x + __int_as_float(y);
}
__device__ __forceinline__ float quad_reduce(float x) {
    return quad_add2(quad_add1(x));
}

__global__ void caps_routing_kernel(
    const float* __restrict__ x, const float* __restrict__ wgt,
    float* __restrict__ out)
{
    __shared__ float lds_w[4 * WSTRIDE];   // 18688 B
    __shared__ float lds_x[XN];            //  5280 B  (total 23968 B/block)

    const int tid = threadIdx.x;
    const int bx  = blockIdx.x;          // n*4 + o
    const int n = bx >> 2, o = bx & 3;

    // block tile: 2 output rows x 8 output cols
    const int by = blockIdx.y;           // 196 = 28 h-blocks x 7 w-blocks
    const int hb = by / 7;
    const int wb = by - hb * 7;
    const int h0 = hb * 2;
    const int w0 = wb * 8;

    // ---- stage weight slice wgt[o][p][k][l][d] (4608 floats) into LDS ----
    {
        const float4* wsrc = (const float4*)(wgt + o * 4608);
        for (int i = tid; i < 1152; i += 256) {
            const int pp  = i / 288;          // 288 float4 per p-plane
            const int rem = i - pp * 288;
            *(float4*)&lds_w[pp * WSTRIDE + rem * 4] = wsrc[i];
        }
    }
    // ---- stage x halo tile: 32 ch x 4 rows x 10 cols, bounds paid once ----
    {
        const float* xn = x + n * 32 * HW2;
        for (int idx = tid; idx < 1280; idx += 256) {
            const int ch  = idx / 40;         // p*8 + l
            const int rem = idx - ch * 40;    // r*10 + c
            const int r   = rem / 10;
            const int c   = rem - r * 10;
            const int gr  = h0 - 1 + r;
            const int gc  = w0 - 1 + c;
            float v = 0.f;
            if ((unsigned)gr < (unsigned)HW && (unsigned)gc < (unsigned)HW)
                v = xn[ch * HW2 + gr * HW + gc];
            lds_x[rem * XSTR + ch] = v;
        }
    }
    __syncthreads();

    const int dq = tid & 3;              // quad bits -> DPP-reducible
    const int wl = (tid >> 2) & 3;
    const int p  = (tid >> 4) & 3;
    const int wi = tid >> 6;             // wave: hh = wi>>1 (row), ww = wi&1 (col grp)
    const int hh = wi >> 1, ww = wi & 1;

    // M[k][j]: priors for the lane's 4 d's at site (h0+hh, w0+ww*4+wl)
    float M[9][4];
    #pragma unroll
    for (int k = 0; k < 9; ++k)
        #pragma unroll
        for (int j = 0; j < 4; ++j) M[k][j] = 0.f;

    // all inner-loop LDS offsets are compile-time immediates off these bases
    const float* xb  = &lds_x[(hh * 10 + ww * 4 + wl) * XSTR + p * 8];
    const float* wbp = &lds_w[p * WSTRIDE + dq * 4];

    #pragma clang loop unroll(disable)
    for (int l = 0; l < 8; ++l) {
        const float* xl  = xb + l;
        const float* wlp = wbp + l * 16;
        // 3 rows (h-1 .. h+1) x 3 cols
        float xv[3][3];
        #pragma unroll
        for (int rr = 0; rr < 3; ++rr)
            #pragma unroll
            for (int c = 0; c < 3; ++c)
                xv[rr][c] = xl[(rr * 10 + c) * XSTR];
        #pragma unroll
        for (int rr = 0; rr < 3; ++rr) {
            #pragma unroll
            for (int kc = 0; kc < 3; ++kc) {
                const int k = rr * 3 + kc;
                const float4 wa = *(const float4*)(wlp + k * 128);
                const float xs = xv[rr][kc];
                M[k][0] += xs * wa.x; M[k][1] += xs * wa.y;
                M[k][2] += xs * wa.z; M[k][3] += xs * wa.w;
            }
        }
    }

    // ---- dynamic routing (3 iters; iter 0 uniform probs = 1/9) ----
    float v[4], b[9];
    {
        float s[4];
        #pragma unroll
        for (int j = 0; j < 4; ++j) {
            float a = M[0][j];
            #pragma unroll
            for (int k = 1; k < 9; ++k) a += M[k][j];
            s[j] = a * (1.f / 9.f);
        }
        float sq = s[0]*s[0] + s[1]*s[1] + s[2]*s[2] + s[3]*s[3];
        sq = quad_reduce(sq);
        const float scale = sq * __builtin_amdgcn_rsqf(sq) * __builtin_amdgcn_rcpf(1.f + sq);
        #pragma unroll
        for (int j = 0; j < 4; ++j) v[j] = s[j] * scale;
        #pragma unroll
        for (int k = 0; k < 9; ++k) {
            float u = M[k][0]*v[0] + M[k][1]*v[1] + M[k][2]*v[2] + M[k][3]*v[3];
            b[k] = quad_reduce(u);
        }
    }

    #pragma unroll
    for (int it = 1; it < 3; ++it) {
        float mx = b[0];
        #pragma unroll
        for (int k = 1; k < 9; ++k) mx = fmaxf(mx, b[k]);
        float e[9]; float se = 0.f;
        #pragma unroll
        for (int k = 0; k < 9; ++k) { e[k] = __expf(b[k] - mx); se += e[k]; }
        const float inv = __builtin_amdgcn_rcpf(se);
        float s[4];
        #pragma unroll
        for (int j = 0; j < 4; ++j) {
            float a = 0.f;
            #pragma unroll
            for (int k = 0; k < 9; ++k) a += e[k] * M[k][j];
            s[j] = a * inv;
        }
        float sq = s[0]*s[0] + s[1]*s[1] + s[2]*s[2] + s[3]*s[3];
        sq = quad_reduce(sq);
        const float scale = sq * __builtin_amdgcn_rsqf(sq) * __builtin_amdgcn_rcpf(1.f + sq);
        #pragma unroll
        for (int j = 0; j < 4; ++j) v[j] = s[j] * scale;
        if (it == 1) {
            #pragma unroll
            for (int k = 0; k < 9; ++k) {
                float u = M[k][0]*v[0] + M[k][1]*v[1] + M[k][2]*v[2] + M[k][3]*v[3];
                b[k] += quad_reduce(u);
            }
        }
    }

    // ---- sum over p (lane bits 4,5), store row h0+hh ----
    #pragma unroll
    for (int j = 0; j < 4; ++j) {
        v[j] += __shfl_xor(v[j], 16, 64);
        v[j] += __shfl_xor(v[j], 32, 64);
    }
    if (p == 0) {
        float* op = out + ((n * 64 + o * 16 + dq * 4) * HW + (h0 + hh)) * HW
                  + w0 + ww * 4 + wl;
        #pragma unroll
        for (int j = 0; j < 4; ++j) op[j * HW2] = v[j];
    }
}

extern "C" void kernel_launch(void* const* d_in, const int* in_sizes, int n_in,
                              void* d_out, int out_size, void* d_ws, size_t ws_size,
                              hipStream_t stream) {
    const float* x   = (const float*)d_in[0];
    const float* wgt = (const float*)d_in[1];
    float* out = (float*)d_out;

    // grid: x = n*4+o (16), y = 196 blocks = 28 h-blocks x 7 w-blocks
    caps_routing_kernel<<<dim3(16, 196), dim3(256), 0, stream>>>(x, wgt, out);
}

// Round 3
// 79.082 us; speedup vs baseline: 1.0344x; 1.0344x over previous
//
#include <hip/hip_runtime.h>

// CapsuleConv2d: x (4,32,56,56) f32, weight (P_out=4,P_in=4,K=9,L_in=8,L_out=16) f32
// out (4,64,56,56) f32. 3x3 conv s1 p1, 3 routing iterations.
//
// Lane = dq(bits 0-1: d-quarter) x wl(bits 2-3: 4 w-sites) x p(bits 4-5: plane).
// dq in the QUAD bits so the d-reduction (squash norm, logit updates) is two DPP
// quad_perm adds (pure VALU, no DS pipe).
//
// EVIDENCE LEDGER (R0/R8/R9 all ~78-82 us bench = ~40.4 us harness ws-fill +
// ~36-40 us kernel):
//   - x path global vs LDS: NEUTRAL (R8).  - 2x weight DS reads: +3 us (R9).
//   - halved per-wave routing chain + grid x2: NEUTRAL (R9).
// => kernel is NOT DS-bound, NOT chain-length-bound, NOT x-path-bound. VALU
// issue is ~10-14 us => ~60% stall at 4-5 waves/SIMD. Occupancy never moved:
// live set stuck ~95-100 VGPR (e[9] + 9 in-flight weight b128s = 36 transient).
//
// R10 (this round): register diet to reach <=84 VGPR -> 6 waves/SIMD (LDS
// 23968 B/block caps blocks/CU at 6 = exactly 6 waves/SIMD):
//   1. e[9] eliminated: exp/se/s[j] fused in one pass (scalar transient).
//   2. sched_barrier(0) between rr-groups in the priors loop: caps in-flight
//      loads at 3 b128 + 3 b32 (~15 regs) instead of 9 b128 (36 regs).
//   3. max3-shaped max tree; s->v scaled in place.
// NO occupancy attributes (R3-R6: caps forced up to 887 MB scratch). All M
// indices compile-time (runtime-indexed arrays go to scratch).

#define HW 56
#define HW2 3136
#define WSTRIDE 1168       // 1152 + 16: p-stride ≡ 16 mod 32 banks (dq*4 spread)
#define XSTR 33            // (r*10+c) stride in floats: wl->+1 bank, p->+8 banks
#define XN (40 * XSTR)     // 1320 floats = 5280 B

// sum over the 4 lanes of a quad: x + quad_perm[1,0,3,2] then + quad_perm[2,3,0,1]
__device__ __forceinline__ float quad_add1(float x) {
    int y = __builtin_amdgcn_update_dpp(0, __float_as_int(x), 0xB1, 0xF, 0xF, true);
    return x + __int_as_float(y);
}
__device__ __forceinline__ float quad_add2(float x) {
    int y = __builtin_amdgcn_update_dpp(0, __float_as_int(x), 0x4E, 0xF, 0xF, true);
    return x + __int_as_float(y);
}
__device__ __forceinline__ float quad_reduce(float x) {
    return quad_add2(quad_add1(x));
}

__global__ void caps_routing_kernel(
    const float* __restrict__ x, const float* __restrict__ wgt,
    float* __restrict__ out)
{
    __shared__ float lds_w[4 * WSTRIDE];   // 18688 B
    __shared__ float lds_x[XN];            //  5280 B  (total 23968 B/block -> 6 blocks/CU)

    const int tid = threadIdx.x;
    const int bx  = blockIdx.x;          // n*4 + o
    const int n = bx >> 2, o = bx & 3;

    // block tile: 2 output rows x 8 output cols
    const int by = blockIdx.y;           // 196 = 28 h-blocks x 7 w-blocks
    const int hb = by / 7;
    const int wb = by - hb * 7;
    const int h0 = hb * 2;
    const int w0 = wb * 8;

    // ---- stage weight slice wgt[o][p][k][l][d] (4608 floats) into LDS ----
    {
        const float4* wsrc = (const float4*)(wgt + o * 4608);
        for (int i = tid; i < 1152; i += 256) {
            const int pp  = i / 288;          // 288 float4 per p-plane
            const int rem = i - pp * 288;
            *(float4*)&lds_w[pp * WSTRIDE + rem * 4] = wsrc[i];
        }
    }
    // ---- stage x halo tile: 32 ch x 4 rows x 10 cols, bounds paid once ----
    {
        const float* xn = x + n * 32 * HW2;
        for (int idx = tid; idx < 1280; idx += 256) {
            const int ch  = idx / 40;         // p*8 + l
            const int rem = idx - ch * 40;    // r*10 + c
            const int r   = rem / 10;
            const int c   = rem - r * 10;
            const int gr  = h0 - 1 + r;
            const int gc  = w0 - 1 + c;
            float v = 0.f;
            if ((unsigned)gr < (unsigned)HW && (unsigned)gc < (unsigned)HW)
                v = xn[ch * HW2 + gr * HW + gc];
            lds_x[rem * XSTR + ch] = v;
        }
    }
    __syncthreads();

    const int dq = tid & 3;              // quad bits -> DPP-reducible
    const int wl = (tid >> 2) & 3;
    const int p  = (tid >> 4) & 3;
    const int wi = tid >> 6;             // wave: hh = wi>>1 (row), ww = wi&1 (col grp)
    const int hh = wi >> 1, ww = wi & 1;

    // M[k][j]: priors for the lane's 4 d's at site (h0+hh, w0+ww*4+wl)
    float M[9][4];
    #pragma unroll
    for (int k = 0; k < 9; ++k)
        #pragma unroll
        for (int j = 0; j < 4; ++j) M[k][j] = 0.f;

    // all inner-loop LDS offsets are compile-time immediates off these bases
    const float* xb  = &lds_x[(hh * 10 + ww * 4 + wl) * XSTR + p * 8];
    const float* wbp = &lds_w[p * WSTRIDE + dq * 4];

    #pragma clang loop unroll(disable)
    for (int l = 0; l < 8; ++l) {
        const float* xl  = xb + l;
        const float* wlp = wbp + l * 16;
        #pragma unroll
        for (int rr = 0; rr < 3; ++rr) {
            // 3 x-values + 3 weight float4s in flight per group (~15 regs),
            // fenced so the scheduler can't hoist all 9 b128s at once.
            const float x0 = xl[(rr * 10 + 0) * XSTR];
            const float x1 = xl[(rr * 10 + 1) * XSTR];
            const float x2 = xl[(rr * 10 + 2) * XSTR];
            const float4 wa0 = *(const float4*)(wlp + (rr * 3 + 0) * 128);
            const float4 wa1 = *(const float4*)(wlp + (rr * 3 + 1) * 128);
            const float4 wa2 = *(const float4*)(wlp + (rr * 3 + 2) * 128);
            M[rr * 3 + 0][0] += x0 * wa0.x; M[rr * 3 + 0][1] += x0 * wa0.y;
            M[rr * 3 + 0][2] += x0 * wa0.z; M[rr * 3 + 0][3] += x0 * wa0.w;
            M[rr * 3 + 1][0] += x1 * wa1.x; M[rr * 3 + 1][1] += x1 * wa1.y;
            M[rr * 3 + 1][2] += x1 * wa1.z; M[rr * 3 + 1][3] += x1 * wa1.w;
            M[rr * 3 + 2][0] += x2 * wa2.x; M[rr * 3 + 2][1] += x2 * wa2.y;
            M[rr * 3 + 2][2] += x2 * wa2.z; M[rr * 3 + 2][3] += x2 * wa2.w;
            __builtin_amdgcn_sched_barrier(0);
        }
    }

    // ---- dynamic routing (3 iters; iter 0 uniform probs = 1/9) ----
    float v[4], b[9];
    {
        #pragma unroll
        for (int j = 0; j < 4; ++j) {
            float a = M[0][j];
            #pragma unroll
            for (int k = 1; k < 9; ++k) a += M[k][j];
            v[j] = a * (1.f / 9.f);
        }
        float sq = v[0]*v[0] + v[1]*v[1] + v[2]*v[2] + v[3]*v[3];
        sq = quad_reduce(sq);
        const float scale = sq * __builtin_amdgcn_rsqf(sq) * __builtin_amdgcn_rcpf(1.f + sq);
        #pragma unroll
        for (int j = 0; j < 4; ++j) v[j] *= scale;
        #pragma unroll
        for (int k = 0; k < 9; ++k) {
            float u = M[k][0]*v[0] + M[k][1]*v[1] + M[k][2]*v[2] + M[k][3]*v[3];
            b[k] = quad_reduce(u);
        }
    }

    #pragma unroll
    for (int it = 1; it < 3; ++it) {
        // max3-shaped tree (clang fuses fmaxf(fmaxf(a,b),c) -> v_max3_f32)
        const float mx = fmaxf(fmaxf(fmaxf(fmaxf(b[0], b[1]), b[2]),
                                     fmaxf(fmaxf(b[3], b[4]), b[5])),
                               fmaxf(fmaxf(b[6], b[7]), b[8]));
        // fused pass: exp, denominator, and the 4 weighted sums (no e[] array)
        float se = 0.f, s0 = 0.f, s1 = 0.f, s2 = 0.f, s3 = 0.f;
        #pragma unroll
        for (int k = 0; k < 9; ++k) {
            const float ek = __expf(b[k] - mx);
            se += ek;
            s0 += ek * M[k][0]; s1 += ek * M[k][1];
            s2 += ek * M[k][2]; s3 += ek * M[k][3];
        }
        const float inv = __builtin_amdgcn_rcpf(se);
        v[0] = s0 * inv; v[1] = s1 * inv; v[2] = s2 * inv; v[3] = s3 * inv;
        float sq = v[0]*v[0] + v[1]*v[1] + v[2]*v[2] + v[3]*v[3];
        sq = quad_reduce(sq);
        const float scale = sq * __builtin_amdgcn_rsqf(sq) * __builtin_amdgcn_rcpf(1.f + sq);
        #pragma unroll
        for (int j = 0; j < 4; ++j) v[j] *= scale;
        if (it == 1) {
            #pragma unroll
            for (int k = 0; k < 9; ++k) {
                float u = M[k][0]*v[0] + M[k][1]*v[1] + M[k][2]*v[2] + M[k][3]*v[3];
                b[k] += quad_reduce(u);
            }
        }
    }

    // ---- sum over p (lane bits 4,5), store row h0+hh ----
    #pragma unroll
    for (int j = 0; j < 4; ++j) {
        v[j] += __shfl_xor(v[j], 16, 64);
        v[j] += __shfl_xor(v[j], 32, 64);
    }
    if (p == 0) {
        float* op = out + ((n * 64 + o * 16 + dq * 4) * HW + (h0 + hh)) * HW
                  + w0 + ww * 4 + wl;
        #pragma unroll
        for (int j = 0; j < 4; ++j) op[j * HW2] = v[j];
    }
}

extern "C" void kernel_launch(void* const* d_in, const int* in_sizes, int n_in,
                              void* d_out, int out_size, void* d_ws, size_t ws_size,
                              hipStream_t stream) {
    const float* x   = (const float*)d_in[0];
    const float* wgt = (const float*)d_in[1];
    float* out = (float*)d_out;

    // grid: x = n*4+o (16), y = 196 blocks = 28 h-blocks x 7 w-blocks
    caps_routing_kernel<<<dim3(16, 196), dim3(256), 0, stream>>>(x, wgt, out);
}

// Round 4
// 77.461 us; speedup vs baseline: 1.0561x; 1.0209x over previous
//
#include <hip/hip_runtime.h>

// CapsuleConv2d: x (4,32,56,56) f32, weight (P_out=4,P_in=4,K=9,L_in=8,L_out=16) f32
// out (4,64,56,56) f32. 3x3 conv s1 p1, 3 routing iterations.
//
// Lane = dq(bits 0-1: d-quarter) x wl(bits 2-3: 4 w-sites) x p(bits 4-5: plane).
// dq in the QUAD bits so the d-reduction (squash norm, logit updates) is two DPP
// quad_perm adds (pure VALU, no DS pipe). T=2: each wave owns two h-adjacent
// sites per w; one ds_read_b128 weight broadcast feeds 8 sites (best DS/site).
//
// EVIDENCE LEDGER (R0=77.97 R8=79.07 R9=81.81 R10=79.08; ws-fill 40.4 us +
// ~25 reset dispatches dominate the bench):
//   - Model B (fits all 4 points): kernel is ~9-12 us, NOT ~38. Structural
//     swings (x global<->LDS, T=2<->T=1, reg diet) move the bench 0-3 us
//     because the kernel is a minor slice near its ~8 us VALU floor.
//   - weight b128 reads are 16-unique-address broadcasts (~3-4 cyc, not 12).
//   - R9 (+2.7): doubling weight-DS/site costs real time -> keep T=2.
//   - R10 (-2.7): routing diet (no e[9], fused pass) helps -> keep it.
//
// R11: R0 structure (T=2, global-x, no x staging) + R10 routing diet. No sched
// fences (global x loads must stay hoistable for latency hiding).
//
// REGISTER LESSONS (R3-R6): any occupancy attribute caused forced spills
// (84/64/128-cap -> up to 887 MB scratch). NO attributes + unroll(disable) on
// the l-loop keeps live ~110, zero scratch. All M indices compile-time.

#define HW 56
#define HW2 3136
#define WSTRIDE 1168       // 1152 + 16: p-stride spreads banks vs dq*4

// sum over the 4 lanes of a quad: x + quad_perm[1,0,3,2] then + quad_perm[2,3,0,1]
__device__ __forceinline__ float quad_add1(float x) {
    int y = __builtin_amdgcn_update_dpp(0, __float_as_int(x), 0xB1, 0xF, 0xF, true);
    return x + __int_as_float(y);
}
__device__ __forceinline__ float quad_add2(float x) {
    int y = __builtin_amdgcn_update_dpp(0, __float_as_int(x), 0x4E, 0xF, 0xF, true);
    return x + __int_as_float(y);
}
__device__ __forceinline__ float quad_reduce(float x) {
    return quad_add2(quad_add1(x));
}

__global__ void caps_routing_kernel(
    const float* __restrict__ x, const float* __restrict__ wgt,
    float* __restrict__ out)
{
    __shared__ float lds_w[4 * WSTRIDE];   // 18688 B

    const int tid = threadIdx.x;
    const int bx  = blockIdx.x;          // n*4 + o
    const int n = bx >> 2, o = bx & 3;

    // ---- stage weight slice wgt[o][p][k][l][d] (4608 floats) into LDS ----
    {
        const float4* wsrc = (const float4*)(wgt + o * 4608);
        for (int i = tid; i < 1152; i += 256) {
            const int pp  = i / 288;          // 288 float4 per p-plane
            const int rem = i - pp * 288;
            *(float4*)&lds_w[pp * WSTRIDE + rem * 4] = wsrc[i];
        }
    }
    __syncthreads();

    const int dq = tid & 3;              // quad bits -> DPP-reducible
    const int wl = (tid >> 2) & 3;
    const int p  = (tid >> 4) & 3;

    // tile-pair index: 392 pairs = 28 h-pairs x 14 w-tiles
    const int t  = blockIdx.y * 4 + (tid >> 6);
    const int hp = t / 14;
    const int w0 = (t - hp * 14) * 4;
    const int h0 = hp * 2;               // wave covers rows h0 and h0+1

    // M[k][j][ti]: priors for the lane's 4 d's at sites (h0+ti, w0+wl)
    float M[9][4][2];
    #pragma unroll
    for (int k = 0; k < 9; ++k)
        #pragma unroll
        for (int j = 0; j < 4; ++j) { M[k][j][0] = 0.f; M[k][j][1] = 0.f; }

    const float* xp = x + (n * 32 + p * 8) * HW2;
    const float* wbase = &lds_w[p * WSTRIDE + dq * 4];
    const int colbase = w0 + wl - 1;

    #pragma clang loop unroll(disable)
    for (int l = 0; l < 8; ++l) {
        // 4 rows (h0-1 .. h0+2) x 3 cols, shared between the two tiles
        float xv[4][3];
        const float* xplane = xp + l * HW2;
        #pragma unroll
        for (int rr = 0; rr < 4; ++rr) {
            const int row = h0 + rr - 1;
            const bool rv = (unsigned)row < (unsigned)HW;
            const float* xrow = xplane + row * HW;
            #pragma unroll
            for (int c = 0; c < 3; ++c) {
                const int col = colbase + c;
                xv[rr][c] = (rv && (unsigned)col < (unsigned)HW) ? xrow[col] : 0.f;
            }
        }
        #pragma unroll
        for (int rr = 0; rr < 3; ++rr) {
            #pragma unroll
            for (int kc = 0; kc < 3; ++kc) {
                const int k = rr * 3 + kc;
                const float4 wa = *(const float4*)(wbase + (k * 8 + l) * 16);
                const float xs0 = xv[rr][kc];       // tile 0 (row h0)
                const float xs1 = xv[rr + 1][kc];   // tile 1 (row h0+1)
                M[k][0][0] += xs0 * wa.x; M[k][1][0] += xs0 * wa.y;
                M[k][2][0] += xs0 * wa.z; M[k][3][0] += xs0 * wa.w;
                M[k][0][1] += xs1 * wa.x; M[k][1][1] += xs1 * wa.y;
                M[k][2][1] += xs1 * wa.z; M[k][3][1] += xs1 * wa.w;
            }
        }
    }

    // ---- dynamic routing (3 iters; iter 0 uniform probs = 1/9), per tile ----
    #pragma unroll
    for (int ti = 0; ti < 2; ++ti) {
        float v[4], b[9];
        {
            #pragma unroll
            for (int j = 0; j < 4; ++j) {
                float a = M[0][j][ti];
                #pragma unroll
                for (int k = 1; k < 9; ++k) a += M[k][j][ti];
                v[j] = a * (1.f / 9.f);
            }
            float sq = v[0]*v[0] + v[1]*v[1] + v[2]*v[2] + v[3]*v[3];
            sq = quad_reduce(sq);
            const float scale = sq * __builtin_amdgcn_rsqf(sq) * __builtin_amdgcn_rcpf(1.f + sq);
            #pragma unroll
            for (int j = 0; j < 4; ++j) v[j] *= scale;
            #pragma unroll
            for (int k = 0; k < 9; ++k) {
                float u = M[k][0][ti]*v[0] + M[k][1][ti]*v[1]
                        + M[k][2][ti]*v[2] + M[k][3][ti]*v[3];
                b[k] = quad_reduce(u);
            }
        }

        #pragma unroll
        for (int it = 1; it < 3; ++it) {
            // max3-shaped tree (clang fuses fmaxf chains -> v_max3_f32)
            const float mx = fmaxf(fmaxf(fmaxf(fmaxf(b[0], b[1]), b[2]),
                                         fmaxf(fmaxf(b[3], b[4]), b[5])),
                                   fmaxf(fmaxf(b[6], b[7]), b[8]));
            // fused pass: exp, denominator, 4 weighted sums (no e[] array)
            float se = 0.f, s0 = 0.f, s1 = 0.f, s2 = 0.f, s3 = 0.f;
            #pragma unroll
            for (int k = 0; k < 9; ++k) {
                const float ek = __expf(b[k] - mx);
                se += ek;
                s0 += ek * M[k][0][ti]; s1 += ek * M[k][1][ti];
                s2 += ek * M[k][2][ti]; s3 += ek * M[k][3][ti];
            }
            const float inv = __builtin_amdgcn_rcpf(se);
            v[0] = s0 * inv; v[1] = s1 * inv; v[2] = s2 * inv; v[3] = s3 * inv;
            float sq = v[0]*v[0] + v[1]*v[1] + v[2]*v[2] + v[3]*v[3];
            sq = quad_reduce(sq);
            const float scale = sq * __builtin_amdgcn_rsqf(sq) * __builtin_amdgcn_rcpf(1.f + sq);
            #pragma unroll
            for (int j = 0; j < 4; ++j) v[j] *= scale;
            if (it == 1) {
                #pragma unroll
                for (int k = 0; k < 9; ++k) {
                    float u = M[k][0][ti]*v[0] + M[k][1][ti]*v[1]
                            + M[k][2][ti]*v[2] + M[k][3][ti]*v[3];
                    b[k] += quad_reduce(u);
                }
            }
        }

        // ---- sum over p (lane bits 4,5), store row h0+ti ----
        #pragma unroll
        for (int j = 0; j < 4; ++j) {
            v[j] += __shfl_xor(v[j], 16, 64);
            v[j] += __shfl_xor(v[j], 32, 64);
        }
        if (p == 0) {
            float* op = out + ((n * 64 + o * 16 + dq * 4) * HW + (h0 + ti)) * HW + w0 + wl;
            #pragma unroll
            for (int j = 0; j < 4; ++j) op[j * HW2] = v[j];
        }
    }
}

extern "C" void kernel_launch(void* const* d_in, const int* in_sizes, int n_in,
                              void* d_out, int out_size, void* d_ws, size_t ws_size,
                              hipStream_t stream) {
    const float* x   = (const float*)d_in[0];
    const float* wgt = (const float*)d_in[1];
    float* out = (float*)d_out;

    // grid: x = n*4+o (16), y = 98 blocks of 4 wave tile-pairs
    //       392 pairs = 28 h-pairs x 14 w-tiles
    caps_routing_kernel<<<dim3(16, 98), dim3(256), 0, stream>>>(x, wgt, out);
}